// Round 11
// baseline (2530.336 us; speedup 1.0000x reference)
//
#include <hip/hip_runtime.h>

#define NN 100000
#define NE 1600000
#define NG 128
#define DIN 20
#define DEMB 300
#define DHID 600
#define DOUT 64
// padded dims
#define DIN_P 32
#define EMB_P 320   // activation storage width (multiple of 64)
#define HID_P 640
#define SCAN_BLK 392  // ceil(NN/256)

static const float BN_EPS_F = 1e-5f;

typedef _Float16 f16x8 __attribute__((ext_vector_type(8)));
typedef float f32x4 __attribute__((ext_vector_type(4)));

// async global->LDS, 16B per lane; LDS dst = wave-uniform base + lane*16
__device__ __forceinline__ void gload_lds16(const void* g, const void* l) {
  __builtin_amdgcn_global_load_lds(
      (const __attribute__((address_space(1))) unsigned int*)(unsigned long long)g,
      (__attribute__((address_space(3))) unsigned int*)(unsigned long long)(unsigned int)(unsigned long long)l,
      16, 0, 0);
}

// ---------------- CSR build (once per call) ----------------

__global__ void count_edges_kernel(const int* __restrict__ dst, const float* __restrict__ ef,
                                   int* __restrict__ counts, float* __restrict__ esum) {
  int e = blockIdx.x * blockDim.x + threadIdx.x;
  if (e >= NE) return;
  int v = dst[e];
  atomicAdd(&counts[v], 1);
  atomicAdd(&esum[v], ef[e]);
}

// 3-phase exclusive scan of counts -> row_ptr/cursor
__global__ __launch_bounds__(256) void scan_part1(const int* __restrict__ counts,
                                                  int* __restrict__ bsums) {
  __shared__ int red[256];
  int t = threadIdx.x;
  int i = blockIdx.x * 256 + t;
  red[t] = (i < NN) ? counts[i] : 0;
  __syncthreads();
  for (int s = 128; s > 0; s >>= 1) {
    if (t < s) red[t] += red[t + s];
    __syncthreads();
  }
  if (t == 0) bsums[blockIdx.x] = red[0];
}

__global__ __launch_bounds__(512) void scan_part2(const int* __restrict__ bsums,
                                                  int* __restrict__ boffs) {
  __shared__ int sc[512];
  int t = threadIdx.x;
  int v = (t < SCAN_BLK) ? bsums[t] : 0;
  sc[t] = v;
  __syncthreads();
  for (int off = 1; off < 512; off <<= 1) {
    int u = (t >= off) ? sc[t - off] : 0;
    __syncthreads();
    sc[t] += u;
    __syncthreads();
  }
  if (t < SCAN_BLK) boffs[t] = sc[t] - v;  // exclusive
}

__global__ __launch_bounds__(256) void scan_part3(const int* __restrict__ counts,
                                                  const int* __restrict__ boffs,
                                                  int* __restrict__ row_ptr,
                                                  int* __restrict__ cursor) {
  __shared__ int sc[256];
  int t = threadIdx.x;
  int i = blockIdx.x * 256 + t;
  int v = (i < NN) ? counts[i] : 0;
  sc[t] = v;
  __syncthreads();
  for (int off = 1; off < 256; off <<= 1) {
    int u = (t >= off) ? sc[t - off] : 0;
    __syncthreads();
    sc[t] += u;
    __syncthreads();
  }
  if (i < NN) {
    int excl = sc[t] - v + boffs[blockIdx.x];
    row_ptr[i] = excl;
    cursor[i] = excl;
  }
  if (i == NN - 1) row_ptr[NN] = NE;
}

__global__ void scatter_kernel(const int* __restrict__ src, const int* __restrict__ dst,
                               int* __restrict__ cursor, int* __restrict__ csr_src) {
  int e = blockIdx.x * blockDim.x + threadIdx.x;
  if (e >= NE) return;
  int pos = atomicAdd(&cursor[dst[e]], 1);
  csr_src[pos] = src[e];
}

// ---------------- weight repack: w[K][Nsrc] fp32 -> wt[Np][Kp] fp16 (transposed, zero-pad) ----

__global__ void repack_wt_kernel(const float* __restrict__ w, _Float16* __restrict__ out,
                                 int K, int Nsrc, int Np, int Kp) {
  int idx = blockIdx.x * blockDim.x + threadIdx.x;
  if (idx >= Np * Kp) return;
  int n = idx / Kp, k = idx - n * Kp;
  float v = (n < Nsrc && k < K) ? w[(size_t)k * Nsrc + n] : 0.f;
  out[idx] = (_Float16)v;
}

__global__ void pad_bias_kernel(const float* __restrict__ b, float* __restrict__ out, int n, int np) {
  int i = blockIdx.x * blockDim.x + threadIdx.x;
  if (i >= np) return;
  out[i] = (i < n) ? b[i] : 0.f;
}

// ---------------- layer-0 spmm: fp32 x[N][20] -> fp16 agg0[N][32] ----------------

__global__ __launch_bounds__(256) void spmm0_kernel(const float* __restrict__ x,
                                                    const int* __restrict__ row_ptr,
                                                    const int* __restrict__ csr_src,
                                                    const float* __restrict__ esum,
                                                    _Float16* __restrict__ out) {
  int wid = (blockIdx.x * blockDim.x + threadIdx.x) >> 6;
  int lane = threadIdx.x & 63;
  if (wid >= NN) return;
  int beg = row_ptr[wid], end = row_ptr[wid + 1];
  float acc = 0.f;
  int j = beg;
  for (; j + 1 < end; j += 2) {
    int s0 = csr_src[j], s1 = csr_src[j + 1];
    if (lane < DIN) {
      acc += x[(size_t)s0 * DIN + lane];
      acc += x[(size_t)s1 * DIN + lane];
    }
  }
  if (j < end) {
    int s0 = csr_src[j];
    if (lane < DIN) acc += x[(size_t)s0 * DIN + lane];
  }
  if (lane < DIN_P) {
    float v = (lane < DIN) ? acc + esum[wid] : 0.f;
    out[(size_t)wid * DIN_P + lane] = (_Float16)v;
  }
}

// ---------------- fused spmm (layers 1..4): gather raw h2 fp16, apply prev BN on the fly ----

__global__ __launch_bounds__(256) void spmm_f16_kernel(const _Float16* __restrict__ x,
                                                       const float* __restrict__ scale,
                                                       const float* __restrict__ shift,
                                                       const int* __restrict__ row_ptr,
                                                       const int* __restrict__ csr_src,
                                                       const float* __restrict__ esum,
                                                       _Float16* __restrict__ out) {
  int wid = (blockIdx.x * blockDim.x + threadIdx.x) >> 6;
  int lane = threadIdx.x & 63;
  if (wid >= NN) return;
  int beg = row_ptr[wid], end = row_ptr[wid + 1];
  float deg = (float)(end - beg);
  float es = esum[wid];
  if (lane >= 40) return;
  const f16x8* xb = (const f16x8*)x;
  float acc[8] = {};
  int j = beg;
  for (; j + 7 < end; j += 8) {
    int s0 = csr_src[j + 0], s1 = csr_src[j + 1], s2 = csr_src[j + 2], s3 = csr_src[j + 3];
    int s4 = csr_src[j + 4], s5 = csr_src[j + 5], s6 = csr_src[j + 6], s7 = csr_src[j + 7];
    f16x8 v0 = xb[(size_t)s0 * 40 + lane];
    f16x8 v1 = xb[(size_t)s1 * 40 + lane];
    f16x8 v2 = xb[(size_t)s2 * 40 + lane];
    f16x8 v3 = xb[(size_t)s3 * 40 + lane];
    f16x8 v4 = xb[(size_t)s4 * 40 + lane];
    f16x8 v5 = xb[(size_t)s5 * 40 + lane];
    f16x8 v6 = xb[(size_t)s6 * 40 + lane];
    f16x8 v7 = xb[(size_t)s7 * 40 + lane];
#pragma unroll
    for (int i = 0; i < 8; ++i) {
      acc[i] += ((float)v0[i] + (float)v1[i]) + ((float)v2[i] + (float)v3[i]) +
                ((float)v4[i] + (float)v5[i]) + ((float)v6[i] + (float)v7[i]);
    }
  }
  for (; j < end; ++j) {
    f16x8 v0 = xb[(size_t)csr_src[j] * 40 + lane];
#pragma unroll
    for (int i = 0; i < 8; ++i) acc[i] += (float)v0[i];
  }
  int c = lane * 8;
  f16x8 o;
#pragma unroll
  for (int i = 0; i < 8; ++i)
    o[i] = (_Float16)(acc[i] * scale[c + i] + deg * shift[c + i] + es);
  ((f16x8*)(out))[(size_t)wid * 40 + lane] = o;
}

// ---------------- big-tile pipelined MFMA GEMM: 256x160 tile, minimal staged bytes ----
// 256 threads = 4 waves stacked in M (wave = 64 rows x 160 cols = 4mf x 10nf).
// BK=32; double-buffered LDS (2 x 26 KB); stage(kc+1) issued right after the barrier
// that consumed stage(kc). Total staged bytes = (N/160)|A| + (M/256)|B| — ~40% less
// than the 128x128 tiling. N dims exact (640=4x160, 320=2x160): no column masking.

template <bool RELU, bool STATS>
__global__ __launch_bounds__(256, 2) void gemm_bt_kernel(const _Float16* __restrict__ A,
                                                         const _Float16* __restrict__ Bt,
                                                         const float* __restrict__ bias,
                                                         _Float16* __restrict__ C,
                                                         int M, int K, int ldC,
                                                         float* __restrict__ stats) {
  const int CH = 26;  // 16 A-chunks + 10 B-chunks, 1 KB each
  __shared__ __align__(16) _Float16 lds[2][26 * 512];
  const int t = threadIdx.x;
  const int wv = t >> 6;
  const int lane = t & 63;
  const int fm = lane & 15;
  const int k8 = (lane >> 4) * 8;
  const int m0 = blockIdx.y * 256;
  const int n0 = blockIdx.x * 160;

  // this wave's staging chunks: c = wv, wv+4, ... (7 max)
  const _Float16* SP[7];
  int ldso[7];
  int nst = 0;
  for (int c = wv; c < CH; c += 4) {
    if (c < 16) {
      int r = min(m0 + c * 16 + fm, M - 1);
      SP[nst] = A + (size_t)r * K + k8;
    } else {
      SP[nst] = Bt + (size_t)(n0 + (c - 16) * 16 + fm) * K + k8;
    }
    ldso[nst] = c * 512 + lane * 8;
    ++nst;
  }

  f32x4 acc[4][10] = {};
  const int nkc = K >> 5;

  // prologue: stage kc=0 into buf 0
  for (int i = 0; i < nst; ++i) gload_lds16(SP[i], &lds[0][ldso[i]]);

  for (int kc = 0; kc < nkc; ++kc) {
    __syncthreads();  // drains stage(kc), issued one compute-phase ago (except kc=0)
    if (kc + 1 < nkc) {
      _Float16* buf = lds[(kc + 1) & 1];
      int ko = (kc + 1) * 32;
      for (int i = 0; i < nst; ++i) gload_lds16(SP[i] + ko, &buf[ldso[i]]);
    }
    const _Float16* bb = lds[kc & 1];
    f16x8 a[4], b[10];
#pragma unroll
    for (int i = 0; i < 4; ++i) a[i] = *(const f16x8*)&bb[(wv * 4 + i) * 512 + lane * 8];
#pragma unroll
    for (int i = 0; i < 10; ++i) b[i] = *(const f16x8*)&bb[(16 + i) * 512 + lane * 8];
#pragma unroll
    for (int mi = 0; mi < 4; ++mi)
#pragma unroll
      for (int ni = 0; ni < 10; ++ni)
        acc[mi][ni] = __builtin_amdgcn_mfma_f32_16x16x32_f16(a[mi], b[ni], acc[mi][ni], 0, 0, 0);
  }

  // epilogue: C/D layout col=lane&15, row=(lane>>4)*4+reg
  float bi[10];
#pragma unroll
  for (int ni = 0; ni < 10; ++ni) bi[ni] = bias[n0 + ni * 16 + fm];
  const int rq = (lane >> 4) * 4;
  float ssum[10], ssq[10];
#pragma unroll
  for (int ni = 0; ni < 10; ++ni) { ssum[ni] = 0.f; ssq[ni] = 0.f; }
#pragma unroll
  for (int mi = 0; mi < 4; ++mi) {
#pragma unroll
    for (int ni = 0; ni < 10; ++ni) {
      int col = n0 + ni * 16 + fm;
#pragma unroll
      for (int r = 0; r < 4; ++r) {
        int row = m0 + (wv * 4 + mi) * 16 + rq + r;
        if (row < M) {
          float v = acc[mi][ni][r] + bi[ni];
          if (RELU) v = fmaxf(v, 0.f);
          C[(size_t)row * ldC + col] = (_Float16)v;
          if (STATS) { ssum[ni] += v; ssq[ni] += v * v; }
        }
      }
    }
  }
  if (STATS) {
    __syncthreads();  // all waves done reading lds as B
    float* sred = (float*)lds;  // 2 x 160 floats
    for (int i = t; i < 320; i += 256) sred[i] = 0.f;
    __syncthreads();
#pragma unroll
    for (int ni = 0; ni < 10; ++ni) {
      int c = ni * 16 + fm;
      atomicAdd(&sred[c], ssum[ni]);
      atomicAdd(&sred[160 + c], ssq[ni]);
    }
    __syncthreads();
    if (t < 160) {
      atomicAdd(&stats[n0 + t], sred[t]);
      atomicAdd(&stats[EMB_P + n0 + t], sred[160 + t]);
    }
  }
}

// ---------------- BN finalize ----------------

__global__ void bn_finalize_kernel(const float* __restrict__ stats, const float* __restrict__ gamma,
                                   const float* __restrict__ beta, float* __restrict__ scale,
                                   float* __restrict__ shift) {
  int c = threadIdx.x;
  if (c >= EMB_P) return;
  if (c < DEMB) {
    float mu = stats[c] / (float)NN;
    float var = fmaxf(stats[EMB_P + c] / (float)NN - mu * mu, 0.f);
    float sc = gamma[c] * rsqrtf(var + BN_EPS_F);
    scale[c] = sc;
    shift[c] = beta[c] - mu * sc;
  } else {
    scale[c] = 0.f;
    shift[c] = 0.f;
  }
}

// ---------------- readout ----------------

#define POOL_BLOCKS 784

__global__ __launch_bounds__(256) void pool2_kernel(const _Float16* __restrict__ h,
                                                    const int* __restrict__ gid,
                                                    float* __restrict__ graw) {
  const int w = (blockIdx.x * 256 + threadIdx.x) >> 6;
  const int lane = threadIdx.x & 63;
  const int NW = POOL_BLOCKS * 4;
  const int rpw = (NN + NW - 1) / NW;
  int r0 = w * rpw, r1 = min(r0 + rpw, NN);
  if (r0 >= r1 || lane >= 40) return;
  const f16x8* hb = (const f16x8*)h;
  float acc[8] = {};
  int curg = gid[r0];
  for (int r = r0; r < r1; ++r) {
    int g = gid[r];
    if (g != curg) {
#pragma unroll
      for (int i = 0; i < 8; ++i) {
        atomicAdd(&graw[curg * EMB_P + lane * 8 + i], acc[i]);
        acc[i] = 0.f;
      }
      curg = g;
    }
    f16x8 v = hb[(size_t)r * 40 + lane];
#pragma unroll
    for (int i = 0; i < 8; ++i) acc[i] += (float)v[i];
  }
#pragma unroll
  for (int i = 0; i < 8; ++i) atomicAdd(&graw[curg * EMB_P + lane * 8 + i], acc[i]);
}

__global__ void final_kernel(const float* __restrict__ graw, const int* __restrict__ gid,
                             const float* __restrict__ scale, const float* __restrict__ shift,
                             const float* __restrict__ wt, const float* __restrict__ bt,
                             float* __restrict__ out) {
  int g = blockIdx.x, t = threadIdx.x;  // 64 threads
  __shared__ int sb[2];
  if (t < 2) {
    int target = g + t;
    int lo = 0, hi = NN;
    while (lo < hi) {
      int m = (lo + hi) >> 1;
      if (gid[m] < target) lo = m + 1; else hi = m;
    }
    sb[t] = lo;
  }
  __syncthreads();
  int cnt = sb[1] - sb[0];
  float inv = cnt > 0 ? 1.0f / (float)cnt : 0.f;
  float sh_on = cnt > 0 ? 1.0f : 0.f;
  float acc = bt[t];
  const float* row = graw + g * EMB_P;
  for (int k = 0; k < DEMB; ++k) {
    float gf = row[k] * inv * scale[k] + sh_on * shift[k];
    acc = fmaf(gf, wt[k * DOUT + t], acc);
  }
  out[g * DOUT + t] = acc;
}

// ---------------- launch ----------------

extern "C" void kernel_launch(void* const* d_in, const int* in_sizes, int n_in,
                              void* d_out, int out_size, void* d_ws, size_t ws_size,
                              hipStream_t stream) {
  const float* node_feats = (const float*)d_in[0];
  const float* edge_feats = (const float*)d_in[1];
  const int* src = (const int*)d_in[2];
  const int* dst = (const int*)d_in[3];
  const int* gid = (const int*)d_in[4];
  const float* w1_0 = (const float*)d_in[5];
  const float* b1_0 = (const float*)d_in[6];
  const float* w2_0 = (const float*)d_in[7];
  const float* b2_0 = (const float*)d_in[8];
  const float* gamma_0 = (const float*)d_in[9];
  const float* beta_0 = (const float*)d_in[10];
  const float* w1s = (const float*)d_in[11];
  const float* b1s = (const float*)d_in[12];
  const float* w2s = (const float*)d_in[13];
  const float* b2s = (const float*)d_in[14];
  const float* gammas = (const float*)d_in[15];
  const float* betas = (const float*)d_in[16];
  const float* wt = (const float*)d_in[17];
  const float* bt = (const float*)d_in[18];
  float* out = (float*)d_out;
  (void)in_sizes; (void)n_in; (void)out_size; (void)ws_size;

  char* ws = (char*)d_ws;
  size_t off = 0;
  auto carve = [&](size_t bytes) -> void* {
    void* p = ws + off;
    off += (bytes + 255) & ~(size_t)255;
    return p;
  };
  _Float16* P0 = (_Float16*)carve((size_t)NN * EMB_P * 2);   // agg (holds [N][32] for l0)
  _Float16* P1 = (_Float16*)carve((size_t)NN * EMB_P * 2);   // raw h2 (pre-BN)
  _Float16* Q  = (_Float16*)carve((size_t)NN * HID_P * 2);   // h1
  float* esum   = (float*)carve((size_t)NN * 4);
  int* counts   = (int*)carve((size_t)NN * 4);
  int* row_ptr  = (int*)carve((size_t)(NN + 1) * 4);
  int* cursor   = (int*)carve((size_t)NN * 4);
  int* csr_src  = (int*)carve((size_t)NE * 4);
  int* bsums    = (int*)carve((size_t)SCAN_BLK * 4);
  int* boffs    = (int*)carve((size_t)SCAN_BLK * 4);
  _Float16* w1t0 = (_Float16*)carve((size_t)HID_P * DIN_P * 2);
  _Float16* w1t  = (_Float16*)carve((size_t)4 * HID_P * EMB_P * 2);
  _Float16* w2t  = (_Float16*)carve((size_t)5 * EMB_P * HID_P * 2);
  float* b1p   = (float*)carve((size_t)5 * HID_P * 4);
  float* b2p   = (float*)carve((size_t)5 * EMB_P * 4);
  float* stats = (float*)carve((size_t)5 * 2 * EMB_P * 4);   // 5 per-layer regions
  float* scale = (float*)carve(EMB_P * 4);
  float* shift = (float*)carve(EMB_P * 4);
  float* graw  = (float*)carve((size_t)NG * EMB_P * 4);

  hipMemsetAsync(esum, 0, (size_t)NN * 4, stream);
  hipMemsetAsync(counts, 0, (size_t)NN * 4, stream);
  hipMemsetAsync(graw, 0, (size_t)NG * EMB_P * 4, stream);
  hipMemsetAsync(stats, 0, (size_t)5 * 2 * EMB_P * 4, stream);  // all 5 layers upfront

  // CSR by dst + per-node edge-feature sums
  count_edges_kernel<<<(NE + 255) / 256, 256, 0, stream>>>(dst, edge_feats, counts, esum);
  scan_part1<<<SCAN_BLK, 256, 0, stream>>>(counts, bsums);
  scan_part2<<<1, 512, 0, stream>>>(bsums, boffs);
  scan_part3<<<SCAN_BLK, 256, 0, stream>>>(counts, boffs, row_ptr, cursor);
  scatter_kernel<<<(NE + 255) / 256, 256, 0, stream>>>(src, dst, cursor, csr_src);

  // weight repacks (fp16, transposed [N][K], exact N)
  repack_wt_kernel<<<(HID_P * DIN_P + 255) / 256, 256, 0, stream>>>(w1_0, w1t0, DIN, DHID, HID_P, DIN_P);
  for (int l = 0; l < 4; ++l) {
    repack_wt_kernel<<<(HID_P * EMB_P + 255) / 256, 256, 0, stream>>>(
        w1s + (size_t)l * DEMB * DHID, w1t + (size_t)l * HID_P * EMB_P, DEMB, DHID, HID_P, EMB_P);
  }
  repack_wt_kernel<<<(EMB_P * HID_P + 255) / 256, 256, 0, stream>>>(w2_0, w2t, DHID, DEMB, EMB_P, HID_P);
  for (int l = 0; l < 4; ++l) {
    repack_wt_kernel<<<(EMB_P * HID_P + 255) / 256, 256, 0, stream>>>(
        w2s + (size_t)l * DHID * DEMB, w2t + (size_t)(l + 1) * EMB_P * HID_P, DHID, DEMB, EMB_P, HID_P);
  }
  pad_bias_kernel<<<(HID_P + 255) / 256, 256, 0, stream>>>(b1_0, b1p, DHID, HID_P);
  pad_bias_kernel<<<(EMB_P + 255) / 256, 256, 0, stream>>>(b2_0, b2p, DEMB, EMB_P);
  for (int l = 0; l < 4; ++l) {
    pad_bias_kernel<<<(HID_P + 255) / 256, 256, 0, stream>>>(b1s + (size_t)l * DHID, b1p + (size_t)(l + 1) * HID_P, DHID, HID_P);
    pad_bias_kernel<<<(EMB_P + 255) / 256, 256, 0, stream>>>(b2s + (size_t)l * DEMB, b2p + (size_t)(l + 1) * EMB_P, DEMB, EMB_P);
  }

  const int MT = (NN + 255) / 256;  // 391 M-tiles
  const int spmm_blocks = (NN * 64 + 255) / 256;

  for (int l = 0; l < 5; ++l) {
    const _Float16* w1t_l = (l == 0) ? w1t0 : w1t + (size_t)(l - 1) * HID_P * EMB_P;
    const _Float16* w2t_l = w2t + (size_t)l * EMB_P * HID_P;
    const float* b1p_l = b1p + (size_t)l * HID_P;
    const float* b2p_l = b2p + (size_t)l * EMB_P;
    const float* ga = (l == 0) ? gamma_0 : gammas + (size_t)(l - 1) * DEMB;
    const float* be = (l == 0) ? beta_0 : betas + (size_t)(l - 1) * DEMB;
    float* stats_l = stats + (size_t)l * 2 * EMB_P;
    int K1 = (l == 0) ? DIN_P : EMB_P;

    if (l == 0) {
      spmm0_kernel<<<spmm_blocks, 256, 0, stream>>>(node_feats, row_ptr, csr_src, esum, P0);
    } else {
      spmm_f16_kernel<<<spmm_blocks, 256, 0, stream>>>(P1, scale, shift, row_ptr, csr_src, esum, P0);
    }

    gemm_bt_kernel<true, false><<<dim3(HID_P / 160, MT), 256, 0, stream>>>(
        P0, w1t_l, b1p_l, Q, NN, K1, HID_P, nullptr);

    gemm_bt_kernel<false, true><<<dim3(EMB_P / 160, MT), 256, 0, stream>>>(
        Q, w2t_l, b2p_l, P1, NN, HID_P, EMB_P, stats_l);

    bn_finalize_kernel<<<1, EMB_P, 0, stream>>>(stats_l, ga, be, scale, shift);
  }

  pool2_kernel<<<POOL_BLOCKS, 256, 0, stream>>>(P1, gid, graw);
  final_kernel<<<NG, 64, 0, stream>>>(graw, gid, scale, shift, wt, bt, out);
}

// Round 12
// 2189.244 us; speedup vs baseline: 1.1558x; 1.1558x over previous
//
#include <hip/hip_runtime.h>

#define NN 100000
#define NE 1600000
#define NG 128
#define DIN 20
#define DEMB 300
#define DHID 600
#define DOUT 64
// padded dims
#define DIN_P 32
#define EMB_P 320   // activation storage width (multiple of 64)
#define HID_P 640
#define EMB_G 384   // gemm2 N-dim padding (multiple of 128)
#define SCAN_BLK 392  // ceil(NN/256)

static const float BN_EPS_F = 1e-5f;

typedef _Float16 f16x8 __attribute__((ext_vector_type(8)));
typedef float f32x4 __attribute__((ext_vector_type(4)));

// async global->LDS, 16B per lane; LDS dst = wave-uniform base + lane*16
__device__ __forceinline__ void gload_lds16(const void* g, const void* l) {
  __builtin_amdgcn_global_load_lds(
      (const __attribute__((address_space(1))) unsigned int*)(unsigned long long)g,
      (__attribute__((address_space(3))) unsigned int*)(unsigned long long)(unsigned int)(unsigned long long)l,
      16, 0, 0);
}

// ---------------- CSR build (once per call) ----------------

__global__ void count_edges_kernel(const int* __restrict__ dst, const float* __restrict__ ef,
                                   int* __restrict__ counts, float* __restrict__ esum) {
  int e = blockIdx.x * blockDim.x + threadIdx.x;
  if (e >= NE) return;
  int v = dst[e];
  atomicAdd(&counts[v], 1);
  atomicAdd(&esum[v], ef[e]);
}

// 3-phase exclusive scan of counts -> row_ptr/cursor
__global__ __launch_bounds__(256) void scan_part1(const int* __restrict__ counts,
                                                  int* __restrict__ bsums) {
  __shared__ int red[256];
  int t = threadIdx.x;
  int i = blockIdx.x * 256 + t;
  red[t] = (i < NN) ? counts[i] : 0;
  __syncthreads();
  for (int s = 128; s > 0; s >>= 1) {
    if (t < s) red[t] += red[t + s];
    __syncthreads();
  }
  if (t == 0) bsums[blockIdx.x] = red[0];
}

__global__ __launch_bounds__(512) void scan_part2(const int* __restrict__ bsums,
                                                  int* __restrict__ boffs) {
  __shared__ int sc[512];
  int t = threadIdx.x;
  int v = (t < SCAN_BLK) ? bsums[t] : 0;
  sc[t] = v;
  __syncthreads();
  for (int off = 1; off < 512; off <<= 1) {
    int u = (t >= off) ? sc[t - off] : 0;
    __syncthreads();
    sc[t] += u;
    __syncthreads();
  }
  if (t < SCAN_BLK) boffs[t] = sc[t] - v;  // exclusive
}

__global__ __launch_bounds__(256) void scan_part3(const int* __restrict__ counts,
                                                  const int* __restrict__ boffs,
                                                  int* __restrict__ row_ptr,
                                                  int* __restrict__ cursor) {
  __shared__ int sc[256];
  int t = threadIdx.x;
  int i = blockIdx.x * 256 + t;
  int v = (i < NN) ? counts[i] : 0;
  sc[t] = v;
  __syncthreads();
  for (int off = 1; off < 256; off <<= 1) {
    int u = (t >= off) ? sc[t - off] : 0;
    __syncthreads();
    sc[t] += u;
    __syncthreads();
  }
  if (i < NN) {
    int excl = sc[t] - v + boffs[blockIdx.x];
    row_ptr[i] = excl;
    cursor[i] = excl;
  }
  if (i == NN - 1) row_ptr[NN] = NE;
}

__global__ void scatter_kernel(const int* __restrict__ src, const int* __restrict__ dst,
                               int* __restrict__ cursor, int* __restrict__ csr_src) {
  int e = blockIdx.x * blockDim.x + threadIdx.x;
  if (e >= NE) return;
  int pos = atomicAdd(&cursor[dst[e]], 1);
  csr_src[pos] = src[e];
}

// ---------------- weight repack: w[K][Nsrc] fp32 -> wt[Np][Kp] fp16 (transposed, zero-pad) ----

__global__ void repack_wt_kernel(const float* __restrict__ w, _Float16* __restrict__ out,
                                 int K, int Nsrc, int Np, int Kp) {
  int idx = blockIdx.x * blockDim.x + threadIdx.x;
  if (idx >= Np * Kp) return;
  int n = idx / Kp, k = idx - n * Kp;
  float v = (n < Nsrc && k < K) ? w[(size_t)k * Nsrc + n] : 0.f;
  out[idx] = (_Float16)v;
}

__global__ void pad_bias_kernel(const float* __restrict__ b, float* __restrict__ out, int n, int np) {
  int i = blockIdx.x * blockDim.x + threadIdx.x;
  if (i >= np) return;
  out[i] = (i < n) ? b[i] : 0.f;
}

// ---------------- layer-0 spmm: fp32 x[N][20] -> fp16 agg0[N][32] ----------------

__global__ __launch_bounds__(256) void spmm0_kernel(const float* __restrict__ x,
                                                    const int* __restrict__ row_ptr,
                                                    const int* __restrict__ csr_src,
                                                    const float* __restrict__ esum,
                                                    _Float16* __restrict__ out) {
  int wid = (blockIdx.x * blockDim.x + threadIdx.x) >> 6;
  int lane = threadIdx.x & 63;
  if (wid >= NN) return;
  int beg = row_ptr[wid], end = row_ptr[wid + 1];
  float acc = 0.f;
  int j = beg;
  for (; j + 1 < end; j += 2) {
    int s0 = csr_src[j], s1 = csr_src[j + 1];
    if (lane < DIN) {
      acc += x[(size_t)s0 * DIN + lane];
      acc += x[(size_t)s1 * DIN + lane];
    }
  }
  if (j < end) {
    int s0 = csr_src[j];
    if (lane < DIN) acc += x[(size_t)s0 * DIN + lane];
  }
  if (lane < DIN_P) {
    float v = (lane < DIN) ? acc + esum[wid] : 0.f;
    out[(size_t)wid * DIN_P + lane] = (_Float16)v;
  }
}

// ---------------- fused spmm (layers 1..4): gather raw h2 fp16, apply prev BN on the fly ----

__global__ __launch_bounds__(256) void spmm_f16_kernel(const _Float16* __restrict__ x,
                                                       const float* __restrict__ scale,
                                                       const float* __restrict__ shift,
                                                       const int* __restrict__ row_ptr,
                                                       const int* __restrict__ csr_src,
                                                       const float* __restrict__ esum,
                                                       _Float16* __restrict__ out) {
  int wid = (blockIdx.x * blockDim.x + threadIdx.x) >> 6;
  int lane = threadIdx.x & 63;
  if (wid >= NN) return;
  int beg = row_ptr[wid], end = row_ptr[wid + 1];
  float deg = (float)(end - beg);
  float es = esum[wid];
  if (lane >= 40) return;
  const f16x8* xb = (const f16x8*)x;
  float acc[8] = {};
  int j = beg;
  for (; j + 7 < end; j += 8) {
    int s0 = csr_src[j + 0], s1 = csr_src[j + 1], s2 = csr_src[j + 2], s3 = csr_src[j + 3];
    int s4 = csr_src[j + 4], s5 = csr_src[j + 5], s6 = csr_src[j + 6], s7 = csr_src[j + 7];
    f16x8 v0 = xb[(size_t)s0 * 40 + lane];
    f16x8 v1 = xb[(size_t)s1 * 40 + lane];
    f16x8 v2 = xb[(size_t)s2 * 40 + lane];
    f16x8 v3 = xb[(size_t)s3 * 40 + lane];
    f16x8 v4 = xb[(size_t)s4 * 40 + lane];
    f16x8 v5 = xb[(size_t)s5 * 40 + lane];
    f16x8 v6 = xb[(size_t)s6 * 40 + lane];
    f16x8 v7 = xb[(size_t)s7 * 40 + lane];
#pragma unroll
    for (int i = 0; i < 8; ++i) {
      acc[i] += ((float)v0[i] + (float)v1[i]) + ((float)v2[i] + (float)v3[i]) +
                ((float)v4[i] + (float)v5[i]) + ((float)v6[i] + (float)v7[i]);
    }
  }
  for (; j < end; ++j) {
    f16x8 v0 = xb[(size_t)csr_src[j] * 40 + lane];
#pragma unroll
    for (int i = 0; i < 8; ++i) acc[i] += (float)v0[i];
  }
  int c = lane * 8;
  f16x8 o;
#pragma unroll
  for (int i = 0; i < 8; ++i)
    o[i] = (_Float16)(acc[i] * scale[c + i] + deg * shift[c + i] + es);
  ((f16x8*)(out))[(size_t)wid * 40 + lane] = o;
}

// ---------------- pipelined 128x128 MFMA GEMM (R7 K-loop) + LDS-staged coalesced epilogue ----
// 256 threads = 4 waves (2x2); block tile 128x128; BK=32; LDS double-buffered (2x16 KB).
// Epilogue: each wave stages its 64x64 C-tile in its own 8 KB LDS quarter, then stores
// f16x8 (128-B contiguous segments) -> full-cacheline writes, no TCC read-modify-write.

template <bool RELU, bool STATS>
__global__ __launch_bounds__(256, 4) void gemm_pipe_kernel(const _Float16* __restrict__ A,
                                                           const _Float16* __restrict__ Bt,
                                                           const float* __restrict__ bias,
                                                           _Float16* __restrict__ C,
                                                           int M, int K, int ldC, int NREAL,
                                                           float* __restrict__ stats) {
  __shared__ __align__(16) _Float16 lds[2][16 * 512];  // 2 x 16 KB; reused as 4 x 8 KB epilogue staging
  const int t = threadIdx.x;
  const int wv = t >> 6;
  const int lane = t & 63;
  const int fm = lane & 15;
  const int k8 = (lane >> 4) * 8;
  const int m0 = blockIdx.y * 128;
  const int n0 = blockIdx.x * 128;
  const int wmq = (wv >> 1) * 4;  // this wave's A-chunk base (x16 rows)
  const int wnq = (wv & 1) * 4;   // this wave's B-chunk base (x16 cols)

  // staging pointers: wave wv stages A-chunks {2wv,2wv+1} and B-chunks {2wv,2wv+1}
  const _Float16* ApS[2];
  const _Float16* BpS[2];
#pragma unroll
  for (int i = 0; i < 2; ++i) {
    int mi = 2 * wv + i;
    int r = min(m0 + mi * 16 + fm, M - 1);
    ApS[i] = A + (size_t)r * K + k8;
    BpS[i] = Bt + (size_t)(n0 + mi * 16 + fm) * K + k8;
  }

  f32x4 acc[4][4] = {};
  const int nkc = K >> 5;

  // prologue: stage kc=0 into buf 0
#pragma unroll
  for (int i = 0; i < 2; ++i) {
    int mi = 2 * wv + i;
    gload_lds16(ApS[i], &lds[0][mi * 512 + lane * 8]);
    gload_lds16(BpS[i], &lds[0][(8 + mi) * 512 + lane * 8]);
  }

  for (int kc = 0; kc < nkc; ++kc) {
    __syncthreads();  // drains stage(kc), issued one compute-phase ago (except kc=0)
    if (kc + 1 < nkc) {
      _Float16* buf = lds[(kc + 1) & 1];
      int ko = (kc + 1) * 32;
#pragma unroll
      for (int i = 0; i < 2; ++i) {
        int mi = 2 * wv + i;
        gload_lds16(ApS[i] + ko, &buf[mi * 512 + lane * 8]);
        gload_lds16(BpS[i] + ko, &buf[(8 + mi) * 512 + lane * 8]);
      }
    }
    const _Float16* bb = lds[kc & 1];
    f16x8 a[4], b[4];
#pragma unroll
    for (int i = 0; i < 4; ++i) a[i] = *(const f16x8*)&bb[(wmq + i) * 512 + lane * 8];
#pragma unroll
    for (int i = 0; i < 4; ++i) b[i] = *(const f16x8*)&bb[(8 + wnq + i) * 512 + lane * 8];
#pragma unroll
    for (int mi = 0; mi < 4; ++mi)
#pragma unroll
      for (int ni = 0; ni < 4; ++ni)
        acc[mi][ni] = __builtin_amdgcn_mfma_f32_16x16x32_f16(a[mi], b[ni], acc[mi][ni], 0, 0, 0);
  }

  // ---- epilogue: stage through per-wave LDS region, store coalesced f16x8 ----
  __syncthreads();  // all waves done reading lds as B staging
  float bi[4];
#pragma unroll
  for (int ni = 0; ni < 4; ++ni) bi[ni] = bias[n0 + (wnq + ni) * 16 + fm];
  const int rq = (lane >> 4) * 4;
  float ssum[4] = {}, ssq[4] = {};
  _Float16* stg = ((_Float16*)lds) + wv * 4096;  // 64x64 halves, this wave's region
#pragma unroll
  for (int mi = 0; mi < 4; ++mi) {
#pragma unroll
    for (int ni = 0; ni < 4; ++ni) {
#pragma unroll
      for (int r = 0; r < 4; ++r) {
        int lr = mi * 16 + rq + r;           // local row 0..63
        int row = m0 + (wv >> 1) * 64 + lr;
        float v = acc[mi][ni][r] + bi[ni];
        if (RELU) v = fmaxf(v, 0.f);
        if (row < M) {
          stg[lr * 64 + ni * 16 + fm] = (_Float16)v;
          if (STATS) { ssum[ni] += v; ssq[ni] += v * v; }
        }
      }
    }
  }
  // per-wave readback (own region; in-wave lgkmcnt ordering suffices)
  {
    const int rr0 = lane >> 3;        // 0..7
    const int c8 = (lane & 7) * 8;    // 0..56
    const int bandc = n0 + wnq * 16;  // wave's 64-col band base (multiple of 64)
    if (bandc < NREAL) {              // NREAL multiple of 64 -> wave-uniform
#pragma unroll
      for (int rr = 0; rr < 8; ++rr) {
        int lr = rr * 8 + rr0;
        int row = m0 + (wv >> 1) * 64 + lr;
        if (row < M)
          *(f16x8*)&C[(size_t)row * ldC + bandc + c8] = *(const f16x8*)&stg[lr * 64 + c8];
      }
    }
  }
  if (STATS) {
    __syncthreads();  // staging regions free for sred
    float* sred = (float*)lds;  // 2 x 128 floats
    if (t < 128) { sred[t] = 0.f; sred[128 + t] = 0.f; }
    __syncthreads();
    const int wn = (wv & 1) * 64;
#pragma unroll
    for (int ni = 0; ni < 4; ++ni) {
      atomicAdd(&sred[wn + ni * 16 + fm], ssum[ni]);
      atomicAdd(&sred[128 + wn + ni * 16 + fm], ssq[ni]);
    }
    __syncthreads();
    if (t < 128) {
      int gc = blockIdx.x * 128 + t;
      atomicAdd(&stats[gc], sred[t]);
      atomicAdd(&stats[EMB_G + gc], sred[128 + t]);
    }
  }
}

// ---------------- BN finalize ----------------

__global__ void bn_finalize_kernel(const float* __restrict__ stats, const float* __restrict__ gamma,
                                   const float* __restrict__ beta, float* __restrict__ scale,
                                   float* __restrict__ shift) {
  int c = threadIdx.x;
  if (c >= EMB_P) return;
  if (c < DEMB) {
    float mu = stats[c] / (float)NN;
    float var = fmaxf(stats[EMB_G + c] / (float)NN - mu * mu, 0.f);
    float sc = gamma[c] * rsqrtf(var + BN_EPS_F);
    scale[c] = sc;
    shift[c] = beta[c] - mu * sc;
  } else {
    scale[c] = 0.f;
    shift[c] = 0.f;
  }
}

// ---------------- readout ----------------

#define POOL_BLOCKS 784

__global__ __launch_bounds__(256) void pool2_kernel(const _Float16* __restrict__ h,
                                                    const int* __restrict__ gid,
                                                    float* __restrict__ graw) {
  const int w = (blockIdx.x * 256 + threadIdx.x) >> 6;
  const int lane = threadIdx.x & 63;
  const int NW = POOL_BLOCKS * 4;
  const int rpw = (NN + NW - 1) / NW;
  int r0 = w * rpw, r1 = min(r0 + rpw, NN);
  if (r0 >= r1 || lane >= 40) return;
  const f16x8* hb = (const f16x8*)h;
  float acc[8] = {};
  int curg = gid[r0];
  for (int r = r0; r < r1; ++r) {
    int g = gid[r];
    if (g != curg) {
#pragma unroll
      for (int i = 0; i < 8; ++i) {
        atomicAdd(&graw[curg * EMB_P + lane * 8 + i], acc[i]);
        acc[i] = 0.f;
      }
      curg = g;
    }
    f16x8 v = hb[(size_t)r * 40 + lane];
#pragma unroll
    for (int i = 0; i < 8; ++i) acc[i] += (float)v[i];
  }
#pragma unroll
  for (int i = 0; i < 8; ++i) atomicAdd(&graw[curg * EMB_P + lane * 8 + i], acc[i]);
}

__global__ void final_kernel(const float* __restrict__ graw, const int* __restrict__ gid,
                             const float* __restrict__ scale, const float* __restrict__ shift,
                             const float* __restrict__ wt, const float* __restrict__ bt,
                             float* __restrict__ out) {
  int g = blockIdx.x, t = threadIdx.x;  // 64 threads
  __shared__ int sb[2];
  if (t < 2) {
    int target = g + t;
    int lo = 0, hi = NN;
    while (lo < hi) {
      int m = (lo + hi) >> 1;
      if (gid[m] < target) lo = m + 1; else hi = m;
    }
    sb[t] = lo;
  }
  __syncthreads();
  int cnt = sb[1] - sb[0];
  float inv = cnt > 0 ? 1.0f / (float)cnt : 0.f;
  float sh_on = cnt > 0 ? 1.0f : 0.f;
  float acc = bt[t];
  const float* row = graw + g * EMB_P;
  for (int k = 0; k < DEMB; ++k) {
    float gf = row[k] * inv * scale[k] + sh_on * shift[k];
    acc = fmaf(gf, wt[k * DOUT + t], acc);
  }
  out[g * DOUT + t] = acc;
}

// ---------------- launch ----------------

extern "C" void kernel_launch(void* const* d_in, const int* in_sizes, int n_in,
                              void* d_out, int out_size, void* d_ws, size_t ws_size,
                              hipStream_t stream) {
  const float* node_feats = (const float*)d_in[0];
  const float* edge_feats = (const float*)d_in[1];
  const int* src = (const int*)d_in[2];
  const int* dst = (const int*)d_in[3];
  const int* gid = (const int*)d_in[4];
  const float* w1_0 = (const float*)d_in[5];
  const float* b1_0 = (const float*)d_in[6];
  const float* w2_0 = (const float*)d_in[7];
  const float* b2_0 = (const float*)d_in[8];
  const float* gamma_0 = (const float*)d_in[9];
  const float* beta_0 = (const float*)d_in[10];
  const float* w1s = (const float*)d_in[11];
  const float* b1s = (const float*)d_in[12];
  const float* w2s = (const float*)d_in[13];
  const float* b2s = (const float*)d_in[14];
  const float* gammas = (const float*)d_in[15];
  const float* betas = (const float*)d_in[16];
  const float* wt = (const float*)d_in[17];
  const float* bt = (const float*)d_in[18];
  float* out = (float*)d_out;
  (void)in_sizes; (void)n_in; (void)out_size; (void)ws_size;

  char* ws = (char*)d_ws;
  size_t off = 0;
  auto carve = [&](size_t bytes) -> void* {
    void* p = ws + off;
    off += (bytes + 255) & ~(size_t)255;
    return p;
  };
  _Float16* P0 = (_Float16*)carve((size_t)NN * EMB_P * 2);   // agg (holds [N][32] for l0)
  _Float16* P1 = (_Float16*)carve((size_t)NN * EMB_P * 2);   // raw h2 (pre-BN)
  _Float16* Q  = (_Float16*)carve((size_t)NN * HID_P * 2);   // h1
  float* esum   = (float*)carve((size_t)NN * 4);
  int* counts   = (int*)carve((size_t)NN * 4);
  int* row_ptr  = (int*)carve((size_t)(NN + 1) * 4);
  int* cursor   = (int*)carve((size_t)NN * 4);
  int* csr_src  = (int*)carve((size_t)NE * 4);
  int* bsums    = (int*)carve((size_t)SCAN_BLK * 4);
  int* boffs    = (int*)carve((size_t)SCAN_BLK * 4);
  _Float16* w1t0 = (_Float16*)carve((size_t)HID_P * DIN_P * 2);
  _Float16* w1t  = (_Float16*)carve((size_t)4 * HID_P * EMB_P * 2);
  _Float16* w2t  = (_Float16*)carve((size_t)5 * EMB_G * HID_P * 2);
  float* b1p   = (float*)carve((size_t)5 * HID_P * 4);
  float* b2p   = (float*)carve((size_t)5 * EMB_G * 4);
  float* stats = (float*)carve((size_t)5 * 2 * EMB_G * 4);   // 5 per-layer regions
  float* scale = (float*)carve(EMB_P * 4);
  float* shift = (float*)carve(EMB_P * 4);
  float* graw  = (float*)carve((size_t)NG * EMB_P * 4);

  hipMemsetAsync(esum, 0, (size_t)NN * 4, stream);
  hipMemsetAsync(counts, 0, (size_t)NN * 4, stream);
  hipMemsetAsync(graw, 0, (size_t)NG * EMB_P * 4, stream);
  hipMemsetAsync(stats, 0, (size_t)5 * 2 * EMB_G * 4, stream);  // all layers upfront

  // CSR by dst + per-node edge-feature sums
  count_edges_kernel<<<(NE + 255) / 256, 256, 0, stream>>>(dst, edge_feats, counts, esum);
  scan_part1<<<SCAN_BLK, 256, 0, stream>>>(counts, bsums);
  scan_part2<<<1, 512, 0, stream>>>(bsums, boffs);
  scan_part3<<<SCAN_BLK, 256, 0, stream>>>(counts, boffs, row_ptr, cursor);
  scatter_kernel<<<(NE + 255) / 256, 256, 0, stream>>>(src, dst, cursor, csr_src);

  // weight repacks (fp16, transposed [Npad][K], zero-padded)
  repack_wt_kernel<<<(HID_P * DIN_P + 255) / 256, 256, 0, stream>>>(w1_0, w1t0, DIN, DHID, HID_P, DIN_P);
  for (int l = 0; l < 4; ++l) {
    repack_wt_kernel<<<(HID_P * EMB_P + 255) / 256, 256, 0, stream>>>(
        w1s + (size_t)l * DEMB * DHID, w1t + (size_t)l * HID_P * EMB_P, DEMB, DHID, HID_P, EMB_P);
  }
  repack_wt_kernel<<<(EMB_G * HID_P + 255) / 256, 256, 0, stream>>>(w2_0, w2t, DHID, DEMB, EMB_G, HID_P);
  for (int l = 0; l < 4; ++l) {
    repack_wt_kernel<<<(EMB_G * HID_P + 255) / 256, 256, 0, stream>>>(
        w2s + (size_t)l * DHID * DEMB, w2t + (size_t)(l + 1) * EMB_G * HID_P, DHID, DEMB, EMB_G, HID_P);
  }
  pad_bias_kernel<<<(HID_P + 255) / 256, 256, 0, stream>>>(b1_0, b1p, DHID, HID_P);
  pad_bias_kernel<<<(EMB_G + 255) / 256, 256, 0, stream>>>(b2_0, b2p, DEMB, EMB_G);
  for (int l = 0; l < 4; ++l) {
    pad_bias_kernel<<<(HID_P + 255) / 256, 256, 0, stream>>>(b1s + (size_t)l * DHID, b1p + (size_t)(l + 1) * HID_P, DHID, HID_P);
    pad_bias_kernel<<<(EMB_G + 255) / 256, 256, 0, stream>>>(b2s + (size_t)l * DEMB, b2p + (size_t)(l + 1) * EMB_G, DEMB, EMB_G);
  }

  const int MT = (NN + 127) / 128;  // 782 M-tiles
  const int spmm_blocks = (NN * 64 + 255) / 256;

  for (int l = 0; l < 5; ++l) {
    const _Float16* w1t_l = (l == 0) ? w1t0 : w1t + (size_t)(l - 1) * HID_P * EMB_P;
    const _Float16* w2t_l = w2t + (size_t)l * EMB_G * HID_P;
    const float* b1p_l = b1p + (size_t)l * HID_P;
    const float* b2p_l = b2p + (size_t)l * EMB_G;
    const float* ga = (l == 0) ? gamma_0 : gammas + (size_t)(l - 1) * DEMB;
    const float* be = (l == 0) ? beta_0 : betas + (size_t)(l - 1) * DEMB;
    float* stats_l = stats + (size_t)l * 2 * EMB_G;
    int K1 = (l == 0) ? DIN_P : EMB_P;

    if (l == 0) {
      spmm0_kernel<<<spmm_blocks, 256, 0, stream>>>(node_feats, row_ptr, csr_src, esum, P0);
    } else {
      spmm_f16_kernel<<<spmm_blocks, 256, 0, stream>>>(P1, scale, shift, row_ptr, csr_src, esum, P0);
    }

    gemm_pipe_kernel<true, false><<<dim3(HID_P / 128, MT), 256, 0, stream>>>(
        P0, w1t_l, b1p_l, Q, NN, K1, HID_P, HID_P, nullptr);

    gemm_pipe_kernel<false, true><<<dim3(EMB_G / 128, MT), 256, 0, stream>>>(
        Q, w2t_l, b2p_l, P1, NN, HID_P, EMB_P, EMB_P, stats_l);

    bn_finalize_kernel<<<1, EMB_P, 0, stream>>>(stats_l, ga, be, scale, shift);
  }

  pool2_kernel<<<POOL_BLOCKS, 256, 0, stream>>>(P1, gid, graw);
  final_kernel<<<NG, 64, 0, stream>>>(graw, gid, scale, shift, wt, bt, out);
}

// Round 13
// 2159.440 us; speedup vs baseline: 1.1718x; 1.0138x over previous
//
#include <hip/hip_runtime.h>

#define NN 100000
#define NE 1600000
#define NG 128
#define DIN 20
#define DEMB 300
#define DHID 600
#define DOUT 64
// padded dims
#define DIN_P 32
#define EMB_P 320   // activation storage width (multiple of 64)
#define HID_P 640
#define EMB_G 384   // gemm2 N-dim padding (multiple of 128)
#define SCAN_BLK 392  // ceil(NN/256)

static const float BN_EPS_F = 1e-5f;

typedef _Float16 f16x8 __attribute__((ext_vector_type(8)));
typedef float f32x4 __attribute__((ext_vector_type(4)));

// async global->LDS, 16B per lane; LDS dst = wave-uniform base + lane*16
__device__ __forceinline__ void gload_lds16(const void* g, const void* l) {
  __builtin_amdgcn_global_load_lds(
      (const __attribute__((address_space(1))) unsigned int*)(unsigned long long)g,
      (__attribute__((address_space(3))) unsigned int*)(unsigned long long)(unsigned int)(unsigned long long)l,
      16, 0, 0);
}

// ---------------- CSR build (once per call) ----------------

__global__ void count_edges_kernel(const int* __restrict__ dst, const float* __restrict__ ef,
                                   int* __restrict__ counts, float* __restrict__ esum) {
  int e = blockIdx.x * blockDim.x + threadIdx.x;
  if (e >= NE) return;
  int v = dst[e];
  atomicAdd(&counts[v], 1);
  atomicAdd(&esum[v], ef[e]);
}

// 3-phase exclusive scan of counts -> row_ptr/cursor
__global__ __launch_bounds__(256) void scan_part1(const int* __restrict__ counts,
                                                  int* __restrict__ bsums) {
  __shared__ int red[256];
  int t = threadIdx.x;
  int i = blockIdx.x * 256 + t;
  red[t] = (i < NN) ? counts[i] : 0;
  __syncthreads();
  for (int s = 128; s > 0; s >>= 1) {
    if (t < s) red[t] += red[t + s];
    __syncthreads();
  }
  if (t == 0) bsums[blockIdx.x] = red[0];
}

__global__ __launch_bounds__(512) void scan_part2(const int* __restrict__ bsums,
                                                  int* __restrict__ boffs) {
  __shared__ int sc[512];
  int t = threadIdx.x;
  int v = (t < SCAN_BLK) ? bsums[t] : 0;
  sc[t] = v;
  __syncthreads();
  for (int off = 1; off < 512; off <<= 1) {
    int u = (t >= off) ? sc[t - off] : 0;
    __syncthreads();
    sc[t] += u;
    __syncthreads();
  }
  if (t < SCAN_BLK) boffs[t] = sc[t] - v;  // exclusive
}

__global__ __launch_bounds__(256) void scan_part3(const int* __restrict__ counts,
                                                  const int* __restrict__ boffs,
                                                  int* __restrict__ row_ptr,
                                                  int* __restrict__ cursor) {
  __shared__ int sc[256];
  int t = threadIdx.x;
  int i = blockIdx.x * 256 + t;
  int v = (i < NN) ? counts[i] : 0;
  sc[t] = v;
  __syncthreads();
  for (int off = 1; off < 256; off <<= 1) {
    int u = (t >= off) ? sc[t - off] : 0;
    __syncthreads();
    sc[t] += u;
    __syncthreads();
  }
  if (i < NN) {
    int excl = sc[t] - v + boffs[blockIdx.x];
    row_ptr[i] = excl;
    cursor[i] = excl;
  }
  if (i == NN - 1) row_ptr[NN] = NE;
}

__global__ void scatter_kernel(const int* __restrict__ src, const int* __restrict__ dst,
                               int* __restrict__ cursor, int* __restrict__ csr_src) {
  int e = blockIdx.x * blockDim.x + threadIdx.x;
  if (e >= NE) return;
  int pos = atomicAdd(&cursor[dst[e]], 1);
  csr_src[pos] = src[e];
}

// ---------------- weight repack: w[K][Nsrc] fp32 -> wt[Np][Kp] fp16 (transposed, zero-pad) ----

__global__ void repack_wt_kernel(const float* __restrict__ w, _Float16* __restrict__ out,
                                 int K, int Nsrc, int Np, int Kp) {
  int idx = blockIdx.x * blockDim.x + threadIdx.x;
  if (idx >= Np * Kp) return;
  int n = idx / Kp, k = idx - n * Kp;
  float v = (n < Nsrc && k < K) ? w[(size_t)k * Nsrc + n] : 0.f;
  out[idx] = (_Float16)v;
}

__global__ void pad_bias_kernel(const float* __restrict__ b, float* __restrict__ out, int n, int np) {
  int i = blockIdx.x * blockDim.x + threadIdx.x;
  if (i >= np) return;
  out[i] = (i < n) ? b[i] : 0.f;
}

// ---------------- layer-0 spmm: fp32 x[N][20] -> fp16 agg0[N][32] ----------------

__global__ __launch_bounds__(256) void spmm0_kernel(const float* __restrict__ x,
                                                    const int* __restrict__ row_ptr,
                                                    const int* __restrict__ csr_src,
                                                    const float* __restrict__ esum,
                                                    _Float16* __restrict__ out) {
  int wid = (blockIdx.x * blockDim.x + threadIdx.x) >> 6;
  int lane = threadIdx.x & 63;
  if (wid >= NN) return;
  int beg = row_ptr[wid], end = row_ptr[wid + 1];
  float acc = 0.f;
  int j = beg;
  for (; j + 1 < end; j += 2) {
    int s0 = csr_src[j], s1 = csr_src[j + 1];
    if (lane < DIN) {
      acc += x[(size_t)s0 * DIN + lane];
      acc += x[(size_t)s1 * DIN + lane];
    }
  }
  if (j < end) {
    int s0 = csr_src[j];
    if (lane < DIN) acc += x[(size_t)s0 * DIN + lane];
  }
  if (lane < DIN_P) {
    float v = (lane < DIN) ? acc + esum[wid] : 0.f;
    out[(size_t)wid * DIN_P + lane] = (_Float16)v;
  }
}

// ---------------- fused spmm (layers 1..4): gather raw h2 fp16, apply prev BN on the fly ----

__global__ __launch_bounds__(256) void spmm_f16_kernel(const _Float16* __restrict__ x,
                                                       const float* __restrict__ scale,
                                                       const float* __restrict__ shift,
                                                       const int* __restrict__ row_ptr,
                                                       const int* __restrict__ csr_src,
                                                       const float* __restrict__ esum,
                                                       _Float16* __restrict__ out) {
  int wid = (blockIdx.x * blockDim.x + threadIdx.x) >> 6;
  int lane = threadIdx.x & 63;
  if (wid >= NN) return;
  int beg = row_ptr[wid], end = row_ptr[wid + 1];
  float deg = (float)(end - beg);
  float es = esum[wid];
  if (lane >= 40) return;
  const f16x8* xb = (const f16x8*)x;
  float acc[8] = {};
  int j = beg;
  for (; j + 7 < end; j += 8) {
    int s0 = csr_src[j + 0], s1 = csr_src[j + 1], s2 = csr_src[j + 2], s3 = csr_src[j + 3];
    int s4 = csr_src[j + 4], s5 = csr_src[j + 5], s6 = csr_src[j + 6], s7 = csr_src[j + 7];
    f16x8 v0 = xb[(size_t)s0 * 40 + lane];
    f16x8 v1 = xb[(size_t)s1 * 40 + lane];
    f16x8 v2 = xb[(size_t)s2 * 40 + lane];
    f16x8 v3 = xb[(size_t)s3 * 40 + lane];
    f16x8 v4 = xb[(size_t)s4 * 40 + lane];
    f16x8 v5 = xb[(size_t)s5 * 40 + lane];
    f16x8 v6 = xb[(size_t)s6 * 40 + lane];
    f16x8 v7 = xb[(size_t)s7 * 40 + lane];
#pragma unroll
    for (int i = 0; i < 8; ++i) {
      acc[i] += ((float)v0[i] + (float)v1[i]) + ((float)v2[i] + (float)v3[i]) +
                ((float)v4[i] + (float)v5[i]) + ((float)v6[i] + (float)v7[i]);
    }
  }
  for (; j < end; ++j) {
    f16x8 v0 = xb[(size_t)csr_src[j] * 40 + lane];
#pragma unroll
    for (int i = 0; i < 8; ++i) acc[i] += (float)v0[i];
  }
  int c = lane * 8;
  f16x8 o;
#pragma unroll
  for (int i = 0; i < 8; ++i)
    o[i] = (_Float16)(acc[i] * scale[c + i] + deg * shift[c + i] + es);
  ((f16x8*)(out))[(size_t)wid * 40 + lane] = o;
}

// ---------------- pipelined 128x128 MFMA GEMM (R12) + XCD-aware 1-D grid swizzle ----
// 256 threads = 4 waves (2x2); block tile 128x128; BK=32; LDS double-buffered (2x16 KB).
// Grid is 1-D: id = yhi*(GX*8) + x*8 + (y&7), so all GX N-tiles sharing one M-tile have
// equal id%8 -> land on the same XCD -> A rows hit that XCD's L2 instead of being
// re-fetched by GX different L2s. Epilogue stages C via per-wave LDS, stores f16x8.

template <bool RELU, bool STATS, int GX>
__global__ __launch_bounds__(256, 4) void gemm_pipe_kernel(const _Float16* __restrict__ A,
                                                           const _Float16* __restrict__ Bt,
                                                           const float* __restrict__ bias,
                                                           _Float16* __restrict__ C,
                                                           int M, int K, int ldC, int NREAL,
                                                           int MT,
                                                           float* __restrict__ stats) {
  __shared__ __align__(16) _Float16 lds[2][16 * 512];  // 2 x 16 KB; reused as 4 x 8 KB epilogue staging
  // XCD-aware decode
  const int id = blockIdx.x;
  const int grp = id / (GX * 8);
  const int rem = id - grp * (GX * 8);
  const int bx = rem >> 3;
  const int by = grp * 8 + (rem & 7);
  if (by >= MT) return;

  const int t = threadIdx.x;
  const int wv = t >> 6;
  const int lane = t & 63;
  const int fm = lane & 15;
  const int k8 = (lane >> 4) * 8;
  const int m0 = by * 128;
  const int n0 = bx * 128;
  const int wmq = (wv >> 1) * 4;  // this wave's A-chunk base (x16 rows)
  const int wnq = (wv & 1) * 4;   // this wave's B-chunk base (x16 cols)

  // staging pointers: wave wv stages A-chunks {2wv,2wv+1} and B-chunks {2wv,2wv+1}
  const _Float16* ApS[2];
  const _Float16* BpS[2];
#pragma unroll
  for (int i = 0; i < 2; ++i) {
    int mi = 2 * wv + i;
    int r = min(m0 + mi * 16 + fm, M - 1);
    ApS[i] = A + (size_t)r * K + k8;
    BpS[i] = Bt + (size_t)(n0 + mi * 16 + fm) * K + k8;
  }

  f32x4 acc[4][4] = {};
  const int nkc = K >> 5;

  // prologue: stage kc=0 into buf 0
#pragma unroll
  for (int i = 0; i < 2; ++i) {
    int mi = 2 * wv + i;
    gload_lds16(ApS[i], &lds[0][mi * 512 + lane * 8]);
    gload_lds16(BpS[i], &lds[0][(8 + mi) * 512 + lane * 8]);
  }

  for (int kc = 0; kc < nkc; ++kc) {
    __syncthreads();  // drains stage(kc), issued one compute-phase ago (except kc=0)
    if (kc + 1 < nkc) {
      _Float16* buf = lds[(kc + 1) & 1];
      int ko = (kc + 1) * 32;
#pragma unroll
      for (int i = 0; i < 2; ++i) {
        int mi = 2 * wv + i;
        gload_lds16(ApS[i] + ko, &buf[mi * 512 + lane * 8]);
        gload_lds16(BpS[i] + ko, &buf[(8 + mi) * 512 + lane * 8]);
      }
    }
    const _Float16* bb = lds[kc & 1];
    f16x8 a[4], b[4];
#pragma unroll
    for (int i = 0; i < 4; ++i) a[i] = *(const f16x8*)&bb[(wmq + i) * 512 + lane * 8];
#pragma unroll
    for (int i = 0; i < 4; ++i) b[i] = *(const f16x8*)&bb[(8 + wnq + i) * 512 + lane * 8];
#pragma unroll
    for (int mi = 0; mi < 4; ++mi)
#pragma unroll
      for (int ni = 0; ni < 4; ++ni)
        acc[mi][ni] = __builtin_amdgcn_mfma_f32_16x16x32_f16(a[mi], b[ni], acc[mi][ni], 0, 0, 0);
  }

  // ---- epilogue: stage through per-wave LDS region, store coalesced f16x8 ----
  __syncthreads();  // all waves done reading lds as B staging
  float bi[4];
#pragma unroll
  for (int ni = 0; ni < 4; ++ni) bi[ni] = bias[n0 + (wnq + ni) * 16 + fm];
  const int rq = (lane >> 4) * 4;
  float ssum[4] = {}, ssq[4] = {};
  _Float16* stg = ((_Float16*)lds) + wv * 4096;  // 64x64 halves, this wave's region
#pragma unroll
  for (int mi = 0; mi < 4; ++mi) {
#pragma unroll
    for (int ni = 0; ni < 4; ++ni) {
#pragma unroll
      for (int r = 0; r < 4; ++r) {
        int lr = mi * 16 + rq + r;           // local row 0..63
        int row = m0 + (wv >> 1) * 64 + lr;
        float v = acc[mi][ni][r] + bi[ni];
        if (RELU) v = fmaxf(v, 0.f);
        if (row < M) {
          stg[lr * 64 + ni * 16 + fm] = (_Float16)v;
          if (STATS) { ssum[ni] += v; ssq[ni] += v * v; }
        }
      }
    }
  }
  // per-wave readback (own region; in-wave lgkmcnt ordering suffices)
  {
    const int rr0 = lane >> 3;        // 0..7
    const int c8 = (lane & 7) * 8;    // 0..56
    const int bandc = n0 + wnq * 16;  // wave's 64-col band base (multiple of 64)
    if (bandc < NREAL) {              // NREAL multiple of 64 -> wave-uniform
#pragma unroll
      for (int rr = 0; rr < 8; ++rr) {
        int lr = rr * 8 + rr0;
        int row = m0 + (wv >> 1) * 64 + lr;
        if (row < M)
          *(f16x8*)&C[(size_t)row * ldC + bandc + c8] = *(const f16x8*)&stg[lr * 64 + c8];
      }
    }
  }
  if (STATS) {
    __syncthreads();  // staging regions free for sred
    float* sred = (float*)lds;  // 2 x 128 floats
    if (t < 128) { sred[t] = 0.f; sred[128 + t] = 0.f; }
    __syncthreads();
    const int wn = (wv & 1) * 64;
#pragma unroll
    for (int ni = 0; ni < 4; ++ni) {
      atomicAdd(&sred[wn + ni * 16 + fm], ssum[ni]);
      atomicAdd(&sred[128 + wn + ni * 16 + fm], ssq[ni]);
    }
    __syncthreads();
    if (t < 128) {
      int gc = bx * 128 + t;
      atomicAdd(&stats[gc], sred[t]);
      atomicAdd(&stats[EMB_G + gc], sred[128 + t]);
    }
  }
}

// ---------------- BN finalize ----------------

__global__ void bn_finalize_kernel(const float* __restrict__ stats, const float* __restrict__ gamma,
                                   const float* __restrict__ beta, float* __restrict__ scale,
                                   float* __restrict__ shift) {
  int c = threadIdx.x;
  if (c >= EMB_P) return;
  if (c < DEMB) {
    float mu = stats[c] / (float)NN;
    float var = fmaxf(stats[EMB_G + c] / (float)NN - mu * mu, 0.f);
    float sc = gamma[c] * rsqrtf(var + BN_EPS_F);
    scale[c] = sc;
    shift[c] = beta[c] - mu * sc;
  } else {
    scale[c] = 0.f;
    shift[c] = 0.f;
  }
}

// ---------------- readout ----------------

#define POOL_BLOCKS 784

__global__ __launch_bounds__(256) void pool2_kernel(const _Float16* __restrict__ h,
                                                    const int* __restrict__ gid,
                                                    float* __restrict__ graw) {
  const int w = (blockIdx.x * 256 + threadIdx.x) >> 6;
  const int lane = threadIdx.x & 63;
  const int NW = POOL_BLOCKS * 4;
  const int rpw = (NN + NW - 1) / NW;
  int r0 = w * rpw, r1 = min(r0 + rpw, NN);
  if (r0 >= r1 || lane >= 40) return;
  const f16x8* hb = (const f16x8*)h;
  float acc[8] = {};
  int curg = gid[r0];
  for (int r = r0; r < r1; ++r) {
    int g = gid[r];
    if (g != curg) {
#pragma unroll
      for (int i = 0; i < 8; ++i) {
        atomicAdd(&graw[curg * EMB_P + lane * 8 + i], acc[i]);
        acc[i] = 0.f;
      }
      curg = g;
    }
    f16x8 v = hb[(size_t)r * 40 + lane];
#pragma unroll
    for (int i = 0; i < 8; ++i) acc[i] += (float)v[i];
  }
#pragma unroll
  for (int i = 0; i < 8; ++i) atomicAdd(&graw[curg * EMB_P + lane * 8 + i], acc[i]);
}

__global__ void final_kernel(const float* __restrict__ graw, const int* __restrict__ gid,
                             const float* __restrict__ scale, const float* __restrict__ shift,
                             const float* __restrict__ wt, const float* __restrict__ bt,
                             float* __restrict__ out) {
  int g = blockIdx.x, t = threadIdx.x;  // 64 threads
  __shared__ int sb[2];
  if (t < 2) {
    int target = g + t;
    int lo = 0, hi = NN;
    while (lo < hi) {
      int m = (lo + hi) >> 1;
      if (gid[m] < target) lo = m + 1; else hi = m;
    }
    sb[t] = lo;
  }
  __syncthreads();
  int cnt = sb[1] - sb[0];
  float inv = cnt > 0 ? 1.0f / (float)cnt : 0.f;
  float sh_on = cnt > 0 ? 1.0f : 0.f;
  float acc = bt[t];
  const float* row = graw + g * EMB_P;
  for (int k = 0; k < DEMB; ++k) {
    float gf = row[k] * inv * scale[k] + sh_on * shift[k];
    acc = fmaf(gf, wt[k * DOUT + t], acc);
  }
  out[g * DOUT + t] = acc;
}

// ---------------- launch ----------------

extern "C" void kernel_launch(void* const* d_in, const int* in_sizes, int n_in,
                              void* d_out, int out_size, void* d_ws, size_t ws_size,
                              hipStream_t stream) {
  const float* node_feats = (const float*)d_in[0];
  const float* edge_feats = (const float*)d_in[1];
  const int* src = (const int*)d_in[2];
  const int* dst = (const int*)d_in[3];
  const int* gid = (const int*)d_in[4];
  const float* w1_0 = (const float*)d_in[5];
  const float* b1_0 = (const float*)d_in[6];
  const float* w2_0 = (const float*)d_in[7];
  const float* b2_0 = (const float*)d_in[8];
  const float* gamma_0 = (const float*)d_in[9];
  const float* beta_0 = (const float*)d_in[10];
  const float* w1s = (const float*)d_in[11];
  const float* b1s = (const float*)d_in[12];
  const float* w2s = (const float*)d_in[13];
  const float* b2s = (const float*)d_in[14];
  const float* gammas = (const float*)d_in[15];
  const float* betas = (const float*)d_in[16];
  const float* wt = (const float*)d_in[17];
  const float* bt = (const float*)d_in[18];
  float* out = (float*)d_out;
  (void)in_sizes; (void)n_in; (void)out_size; (void)ws_size;

  char* ws = (char*)d_ws;
  size_t off = 0;
  auto carve = [&](size_t bytes) -> void* {
    void* p = ws + off;
    off += (bytes + 255) & ~(size_t)255;
    return p;
  };
  _Float16* P0 = (_Float16*)carve((size_t)NN * EMB_P * 2);   // agg (holds [N][32] for l0)
  _Float16* P1 = (_Float16*)carve((size_t)NN * EMB_P * 2);   // raw h2 (pre-BN)
  _Float16* Q  = (_Float16*)carve((size_t)NN * HID_P * 2);   // h1
  float* esum   = (float*)carve((size_t)NN * 4);
  int* counts   = (int*)carve((size_t)NN * 4);
  int* row_ptr  = (int*)carve((size_t)(NN + 1) * 4);
  int* cursor   = (int*)carve((size_t)NN * 4);
  int* csr_src  = (int*)carve((size_t)NE * 4);
  int* bsums    = (int*)carve((size_t)SCAN_BLK * 4);
  int* boffs    = (int*)carve((size_t)SCAN_BLK * 4);
  _Float16* w1t0 = (_Float16*)carve((size_t)HID_P * DIN_P * 2);
  _Float16* w1t  = (_Float16*)carve((size_t)4 * HID_P * EMB_P * 2);
  _Float16* w2t  = (_Float16*)carve((size_t)5 * EMB_G * HID_P * 2);
  float* b1p   = (float*)carve((size_t)5 * HID_P * 4);
  float* b2p   = (float*)carve((size_t)5 * EMB_G * 4);
  float* stats = (float*)carve((size_t)5 * 2 * EMB_G * 4);   // 5 per-layer regions
  float* scale = (float*)carve(EMB_P * 4);
  float* shift = (float*)carve(EMB_P * 4);
  float* graw  = (float*)carve((size_t)NG * EMB_P * 4);

  hipMemsetAsync(esum, 0, (size_t)NN * 4, stream);
  hipMemsetAsync(counts, 0, (size_t)NN * 4, stream);
  hipMemsetAsync(graw, 0, (size_t)NG * EMB_P * 4, stream);
  hipMemsetAsync(stats, 0, (size_t)5 * 2 * EMB_G * 4, stream);  // all layers upfront

  // CSR by dst + per-node edge-feature sums
  count_edges_kernel<<<(NE + 255) / 256, 256, 0, stream>>>(dst, edge_feats, counts, esum);
  scan_part1<<<SCAN_BLK, 256, 0, stream>>>(counts, bsums);
  scan_part2<<<1, 512, 0, stream>>>(bsums, boffs);
  scan_part3<<<SCAN_BLK, 256, 0, stream>>>(counts, boffs, row_ptr, cursor);
  scatter_kernel<<<(NE + 255) / 256, 256, 0, stream>>>(src, dst, cursor, csr_src);

  // weight repacks (fp16, transposed [Npad][K], zero-padded)
  repack_wt_kernel<<<(HID_P * DIN_P + 255) / 256, 256, 0, stream>>>(w1_0, w1t0, DIN, DHID, HID_P, DIN_P);
  for (int l = 0; l < 4; ++l) {
    repack_wt_kernel<<<(HID_P * EMB_P + 255) / 256, 256, 0, stream>>>(
        w1s + (size_t)l * DEMB * DHID, w1t + (size_t)l * HID_P * EMB_P, DEMB, DHID, HID_P, EMB_P);
  }
  repack_wt_kernel<<<(EMB_G * HID_P + 255) / 256, 256, 0, stream>>>(w2_0, w2t, DHID, DEMB, EMB_G, HID_P);
  for (int l = 0; l < 4; ++l) {
    repack_wt_kernel<<<(EMB_G * HID_P + 255) / 256, 256, 0, stream>>>(
        w2s + (size_t)l * DHID * DEMB, w2t + (size_t)(l + 1) * EMB_G * HID_P, DHID, DEMB, EMB_G, HID_P);
  }
  pad_bias_kernel<<<(HID_P + 255) / 256, 256, 0, stream>>>(b1_0, b1p, DHID, HID_P);
  pad_bias_kernel<<<(EMB_G + 255) / 256, 256, 0, stream>>>(b2_0, b2p, DEMB, EMB_G);
  for (int l = 0; l < 4; ++l) {
    pad_bias_kernel<<<(HID_P + 255) / 256, 256, 0, stream>>>(b1s + (size_t)l * DHID, b1p + (size_t)(l + 1) * HID_P, DHID, HID_P);
    pad_bias_kernel<<<(EMB_G + 255) / 256, 256, 0, stream>>>(b2s + (size_t)l * DEMB, b2p + (size_t)(l + 1) * EMB_G, DEMB, EMB_G);
  }

  const int MT = (NN + 127) / 128;           // 782 M-tiles
  const int MT8 = ((MT + 7) / 8) * 8;        // 784 (padded for XCD decode)
  const int spmm_blocks = (NN * 64 + 255) / 256;

  for (int l = 0; l < 5; ++l) {
    const _Float16* w1t_l = (l == 0) ? w1t0 : w1t + (size_t)(l - 1) * HID_P * EMB_P;
    const _Float16* w2t_l = w2t + (size_t)l * EMB_G * HID_P;
    const float* b1p_l = b1p + (size_t)l * HID_P;
    const float* b2p_l = b2p + (size_t)l * EMB_G;
    const float* ga = (l == 0) ? gamma_0 : gammas + (size_t)(l - 1) * DEMB;
    const float* be = (l == 0) ? beta_0 : betas + (size_t)(l - 1) * DEMB;
    float* stats_l = stats + (size_t)l * 2 * EMB_G;
    int K1 = (l == 0) ? DIN_P : EMB_P;

    if (l == 0) {
      spmm0_kernel<<<spmm_blocks, 256, 0, stream>>>(node_feats, row_ptr, csr_src, esum, P0);
    } else {
      spmm_f16_kernel<<<spmm_blocks, 256, 0, stream>>>(P1, scale, shift, row_ptr, csr_src, esum, P0);
    }

    gemm_pipe_kernel<true, false, 5><<<5 * MT8, 256, 0, stream>>>(
        P0, w1t_l, b1p_l, Q, NN, K1, HID_P, HID_P, MT, nullptr);

    gemm_pipe_kernel<false, true, 3><<<3 * MT8, 256, 0, stream>>>(
        Q, w2t_l, b2p_l, P1, NN, HID_P, EMB_P, EMB_P, MT, stats_l);

    bn_finalize_kernel<<<1, EMB_P, 0, stream>>>(stats_l, ga, be, scale, shift);
  }

  pool2_kernel<<<POOL_BLOCKS, 256, 0, stream>>>(P1, gid, graw);
  final_kernel<<<NG, 64, 0, stream>>>(graw, gid, scale, shift, wt, bt, out);
}